// Round 6
// baseline (412.433 us; speedup 1.0000x reference)
//
#include <hip/hip_runtime.h>
#include <hip/hip_bf16.h>

typedef __attribute__((ext_vector_type(8))) short short8_t;
typedef __attribute__((ext_vector_type(4))) float floatx4;
typedef __attribute__((ext_vector_type(2))) float floatx2;
typedef unsigned short ushort_t;
typedef unsigned int uint_t;

// LDS ring: 32 row-slots; slot = 18 cols x 64 ci bf16 = 1152 ushorts (2304 B).
// col layout: 64 ushorts per col, as 8 x 16B ci-octet chunks, chunk index
// XOR-swizzled with (col&7)  ->  frag b128 reads and b16 writes both <=2-way.
#define SLOT_US 1152
#define NSLOT   32

__device__ __forceinline__ uint_t rne_u(float f) {
    uint_t u = __float_as_uint(f);
    return u + (0x7fffu + ((u >> 16) & 1u));   // bf16(f) in bits[31:16], RNE
}

// one-time transpose/convert: w2[co][khw*64+ci] = bf16(w[co][ci*9+khw])
__global__ void w2_prepass(const float* __restrict__ w, ushort_t* __restrict__ w2) {
    int idx = blockIdx.x * 256 + threadIdx.x;  // exactly 73728
    int co  = idx / 576;
    int k   = idx - co * 576;
    int khw = k >> 6, ci = k & 63;
    w2[idx] = (ushort_t)(rne_u(w[co * 576 + ci * 9 + khw]) >> 16);
}

// Block = (n, 16-wide wo strip). 512 thr = 8 waves (2 m-halves x 4 co-slots).
// Loops 16 ho-groups of 8 rows; M=128 (8 ho x 16 wo) x N=128, K=576 per group.
// x rows stream through a 32-slot LDS ring; loads for group g+1 issue before
// group g's rounds consume the ring -> continuous HBM trickle, 2 barriers/group.
__global__ __launch_bounds__(512, 2)
void conv_min_tanh_kernel(const float* __restrict__ x,
                          const float* __restrict__ w,
                          const ushort_t* __restrict__ w2,
                          const float* __restrict__ bias,
                          float* __restrict__ out,
                          int use_w2)
{
    __shared__ ushort_t T[NSLOT * SLOT_US];   // 73,728 B
    __shared__ float red[128][4];             // 2,048 B

    const int tid = threadIdx.x;
    const int n   = blockIdx.x >> 3;
    const int s   = blockIdx.x & 7;
    const int c0  = s * 16;                   // x col base; cols c0..c0+17 used

    // staging geometry: one thread per (ci, row-within-batch)
    const int ci = tid & 63;
    const int rr = tid >> 6;                  // 0..7, wave-uniform

    // wave geometry
    const int lane = tid & 63;
    const int wid  = tid >> 6;
    const int wm   = wid >> 2;                // m-half (64 rows)
    const int wn   = wid & 3;                 // co-slot (32 co)
    const int r16  = lane & 15;
    const int quad = lane >> 4;

    const float* xci = x + ((size_t)n << 20) + (size_t)ci * 16384 + c0;
    const int tail_off = (s == 7) ? 14 : 16;  // clamp cols 128/129 -> 126/127 (pad-only)

    // stage one x row (r < 128) into ring slot r&31
    auto stage_row = [&](int r) {
        const float* p = xci + r * 128;
        floatx4 v0 = *reinterpret_cast<const floatx4*>(p);
        floatx4 v1 = *reinterpret_cast<const floatx4*>(p + 4);
        floatx4 v2 = *reinterpret_cast<const floatx4*>(p + 8);
        floatx4 v3 = *reinterpret_cast<const floatx4*>(p + 12);
        floatx2 v4 = *reinterpret_cast<const floatx2*>(p + tail_off);
        float dv[18];
#pragma unroll
        for (int i = 0; i < 4; ++i) { dv[i] = v0[i]; dv[4+i] = v1[i]; dv[8+i] = v2[i]; dv[12+i] = v3[i]; }
        dv[16] = v4[0]; dv[17] = v4[1];
        ushort_t* base = &T[(r & 31) * SLOT_US];
#pragma unroll
        for (int cl = 0; cl < 18; ++cl) {
            int chunk = (ci >> 3) ^ (cl & 7);
            base[cl * 64 + chunk * 8 + (ci & 7)] = (ushort_t)(rne_u(dv[cl]) >> 16);
        }
    };

    // precomputed frag column offsets (ushort units) for kw x ci-half
    int colpart[3][2];
#pragma unroll
    for (int kw = 0; kw < 3; ++kw)
#pragma unroll
        for (int h = 0; h < 2; ++h) {
            int c = r16 + kw;
            colpart[kw][h] = c * 64 + (((h * 4 + quad) ^ (c & 7)) * 8);
        }

    const ushort_t* w2base = w2 + (size_t)(wn * 32 + r16) * 576 + quad * 8;
    const float*    wbase  = w + (size_t)(wn * 32 + r16) * 576;   // fallback

    float bias_v[2];
#pragma unroll
    for (int bf = 0; bf < 2; ++bf)
        bias_v[bf] = bias[wn * 32 + bf * 16 + r16];

    // prologue: stage rows 0..9
    stage_row(rr);
    if (rr < 2) stage_row(rr + 8);
    __syncthreads();

    for (int g = 0; g < 16; ++g) {
        // ---- issue next batch's loads NOW (rows g*8+10 .. g*8+17) ----
        const int rnew = g * 8 + 10 + rr;
        float dv[18];
        bool have_new = (rnew < 128);         // wave-uniform
        if (have_new) {
            const float* p = xci + rnew * 128;
            floatx4 v0 = *reinterpret_cast<const floatx4*>(p);
            floatx4 v1 = *reinterpret_cast<const floatx4*>(p + 4);
            floatx4 v2 = *reinterpret_cast<const floatx4*>(p + 8);
            floatx4 v3 = *reinterpret_cast<const floatx4*>(p + 12);
            floatx2 v4 = *reinterpret_cast<const floatx2*>(p + tail_off);
#pragma unroll
            for (int i = 0; i < 4; ++i) { dv[i] = v0[i]; dv[4+i] = v1[i]; dv[8+i] = v2[i]; dv[12+i] = v3[i]; }
            dv[16] = v4[0]; dv[17] = v4[1];
        }

        // ---- 18 MFMA rounds off the ring (rows g*8 .. g*8+9) ----
        floatx4 acc[4][2];
#pragma unroll
        for (int tf = 0; tf < 4; ++tf)
#pragma unroll
            for (int bf = 0; bf < 2; ++bf)
                acc[tf][bf] = (floatx4){0.f, 0.f, 0.f, 0.f};

        short8_t bcur[2], bnxt[2];
        if (use_w2) {
#pragma unroll
            for (int bf = 0; bf < 2; ++bf)
                bcur[bf] = *reinterpret_cast<const short8_t*>(w2base + (size_t)bf * (16 * 576));
        } else {
#pragma unroll
            for (int bf = 0; bf < 2; ++bf) {
                short8_t b;
#pragma unroll
                for (int j = 0; j < 8; ++j) {
                    int k = quad * 8 + j;   // khw=0, half=0
                    b[j] = (short)(rne_u(wbase[(size_t)bf * (16 * 576) + k * 9]) >> 16);
                }
                bcur[bf] = b;
            }
        }

#pragma unroll
        for (int rd = 0; rd < 18; ++rd) {
            const int khw = rd >> 1, h = rd & 1;
            const int kh  = khw / 3, kw = khw - kh * 3;

            if (rd < 17) {
                const int khw2 = (rd + 1) >> 1, h2 = (rd + 1) & 1;
                if (use_w2) {
                    const ushort_t* bb = w2base + khw2 * 64 + h2 * 32;
#pragma unroll
                    for (int bf = 0; bf < 2; ++bf)
                        bnxt[bf] = *reinterpret_cast<const short8_t*>(bb + (size_t)bf * (16 * 576));
                } else {
#pragma unroll
                    for (int bf = 0; bf < 2; ++bf) {
                        short8_t b;
#pragma unroll
                        for (int j = 0; j < 8; ++j) {
                            int k = h2 * 32 + quad * 8 + j;
                            b[j] = (short)(rne_u(wbase[(size_t)bf * (16 * 576) + k * 9 + khw2]) >> 16);
                        }
                        bnxt[bf] = b;
                    }
                }
            }

            short8_t afr[4];
#pragma unroll
            for (int tf = 0; tf < 4; ++tf) {
                int row = g * 8 + wm * 4 + tf + kh;
                if (row > 127) row = 127;     // pad-ho rows only (discarded)
                afr[tf] = *reinterpret_cast<const short8_t*>(
                    &T[(row & 31) * SLOT_US + colpart[kw][h]]);
            }
#pragma unroll
            for (int tf = 0; tf < 4; ++tf)
#pragma unroll
                for (int bf = 0; bf < 2; ++bf)
                    acc[tf][bf] = __builtin_amdgcn_mfma_f32_16x16x32_bf16(
                        afr[tf], bcur[bf], acc[tf][bf], 0, 0, 0);
#pragma unroll
            for (int bf = 0; bf < 2; ++bf)
                bcur[bf] = bnxt[bf];
        }

        // ---- convert + ring-write the new rows (slots disjoint from reads) ----
        if (have_new) {
            ushort_t* base = &T[(rnew & 31) * SLOT_US];
#pragma unroll
            for (int cl = 0; cl < 18; ++cl) {
                int chunk = (ci >> 3) ^ (cl & 7);
                base[cl * 64 + chunk * 8 + (ci & 7)] = (ushort_t)(rne_u(dv[cl]) >> 16);
            }
        }

        // ---- epilogue: +bias, min over co, tanh(tanh), store ----
#pragma unroll
        for (int tf = 0; tf < 4; ++tf) {
#pragma unroll
            for (int r = 0; r < 4; ++r) {
                // C/D: row(m) = quad*4+r, col(co) = r16
                float v = fminf(acc[tf][0][r] + bias_v[0], acc[tf][1][r] + bias_v[1]);
                v = fminf(v, __shfl_xor(v, 1, 64));
                v = fminf(v, __shfl_xor(v, 2, 64));
                v = fminf(v, __shfl_xor(v, 4, 64));
                v = fminf(v, __shfl_xor(v, 8, 64));
                if (r16 == 0)
                    red[wm * 64 + tf * 16 + quad * 4 + r][wn] = v;
            }
        }
        __syncthreads();   // red ready AND staging writes visible for next group

        if (tid < 128) {
            const int ho = g * 8 + (tid >> 4);
            const int wo = c0 + (tid & 15);
            if (ho < 126 && wo < 126) {
                float v = fminf(fminf(red[tid][0], red[tid][1]),
                                fminf(red[tid][2], red[tid][3]));
                v = tanhf(tanhf(v));
                out[((size_t)n * 126 + ho) * 126 + wo] = v;
            }
        }
        __syncthreads();   // red reads done before next group's epilogue writes
    }
}

extern "C" void kernel_launch(void* const* d_in, const int* in_sizes, int n_in,
                              void* d_out, int out_size, void* d_ws, size_t ws_size,
                              hipStream_t stream) {
    const float* x    = (const float*)d_in[0];   // [32,64,128,128] f32
    const float* w    = (const float*)d_in[1];   // [128,64,3,3] f32
    const float* bias = (const float*)d_in[2];   // [128] f32
    float* out = (float*)d_out;                  // [32,1,126,126] f32

    const int use_w2 = (ws_size >= (size_t)(73728 * 2)) ? 1 : 0;
    ushort_t* w2 = (ushort_t*)d_ws;

    if (use_w2)
        w2_prepass<<<dim3(288), dim3(256), 0, stream>>>(w, w2);

    // 32 images x 8 wo-strips = 256 blocks (1 per CU), persistent over 16 ho-groups
    conv_min_tanh_kernel<<<dim3(256), dim3(512), 0, stream>>>(x, w, w2, bias, out, use_w2);
}